// Round 4
// baseline (7102.792 us; speedup 1.0000x reference)
//
#include <hip/hip_runtime.h>

#define T_LEN 2048

typedef _Float16 f16x8 __attribute__((ext_vector_type(8)));
typedef float f32x4 __attribute__((ext_vector_type(4)));
typedef unsigned int u32;

__device__ __forceinline__ float sigm(float v) { return 1.f / (1.f + __expf(-v)); }

// XOR-swizzled address into the A tile: [16 rows (seq)][512 k] f16.
__device__ __forceinline__ void* swzA(_Float16* base, int row, int khalf) {
  int byte = row * 1024 + khalf * 2;  // khalf multiple of 8 -> 16B aligned
  byte ^= (row & 7) << 4;
  return (void*)((char*)base + byte);
}

// Grid: 32 WGs x 256 threads.
//  group g = blockIdx&3: {dir, batch-half} -> 16 sequences
//  member m = blockIdx>>2: owns h-dims [32m..32m+31]
//  wave w: owns 8 dims (mw8..+7) x ALL 4 gate parts:
//    tile0 cols: 0..7 = part i, 8..15 = part f   (both sigmoid)
//    tile1 cols: 0..7 = part j, 8..15 = part o   (tanh / sigmoid)
// Exchange lines: u32 {hi16 = stamp t+1, lo16 = f16 h}, double-buffered by t&1,
// agent-scope relaxed atomics. memset(0) per launch; stamps 1..2048 fit 16b.
__global__ __launch_bounds__(256, 1) void bilstm_kernel(
    const float* __restrict__ x, const float* __restrict__ Wfw,
    const float* __restrict__ bfw, const float* __restrict__ Wbw,
    const float* __restrict__ bbw, float* __restrict__ out,
    u32* __restrict__ hglob) {
  const int g = blockIdx.x & 3;
  const int m = blockIdx.x >> 2;
  const int dir = g >> 1, bh = g & 1;
  const int tid = threadIdx.x;
  const int w = tid >> 6;
  const int lane = tid & 63;
  const int l15 = lane & 15, l4 = lane >> 4;
  const bool lo8 = (l15 < 8);
  const int d8 = l15 & 7;
  const int mw8 = m * 32 + w * 8;

  const float* W = dir ? Wbw : Wfw;
  const float* bias = dir ? bbw : bfw;

  __shared__ _Float16 Alds[16 * 512];  // 16KB swizzled [seq][k<256:x, k>=256:h]

  // gate-column mapping for this lane
  const int gc0 = (lo8 ? 0 : 512) + mw8 + d8;   // i | f
  const int gc1 = (lo8 ? 256 : 768) + mw8 + d8; // j | o

  // ---- weight fragments: lane l holds B[k=8*l4+j][col=l15] ----
  f16x8 wB0[16], wB1[16];
#pragma unroll
  for (int kk = 0; kk < 16; ++kk) {
    const int kb = kk * 32 + l4 * 8;
    f16x8 h0, h1;
#pragma unroll
    for (int j = 0; j < 8; ++j) {
      h0[j] = (_Float16)W[(kb + j) * 1024 + gc0];
      h1[j] = (_Float16)W[(kb + j) * 1024 + gc1];
    }
    wB0[kk] = h0;
    wB1[kk] = h1;
  }
  const float b0 = bias[gc0] + (lo8 ? 0.f : 1.f);  // forget bias folded
  const float b1 = bias[gc1];

  // staging/poll mapping: thread -> (seq ss, chunk si): dims {8si..+7, 128+8si..+7}
  const int ss = tid >> 4;
  const int si = tid & 15;
  const int dA = 8 * si, dB = 128 + 8 * si;

  u32* Hg = hglob + g * (2 * 16 * 256);

  float c[4] = {0.f, 0.f, 0.f, 0.f};  // cell state, lanes lo8, seqs 4*l4+v

  // prologue: zero h-region; prefetch x_0
  {
    uint4 z = {0u, 0u, 0u, 0u};
    *(uint4*)swzA(Alds, ss, 256 + dA) = z;
    *(uint4*)swzA(Alds, ss, 256 + dB) = z;
  }
  const int tx0 = dir ? (T_LEN - 1) : 0;
  const float* xr0 = x + (((bh * 16 + ss) * T_LEN + tx0) << 8);
  f32x4 xa0 = *(const f32x4*)(xr0 + dA);
  f32x4 xa1 = *(const f32x4*)(xr0 + dA + 4);
  f32x4 xb0 = *(const f32x4*)(xr0 + dB);
  f32x4 xb1 = *(const f32x4*)(xr0 + dB + 4);

#define LOADQ(q)                                                              \
  {                                                                           \
    _Pragma("unroll") for (int j_ = 0; j_ < 8; ++j_) q[j_] =                  \
        __hip_atomic_load(hp + dA + j_, __ATOMIC_RELAXED,                     \
                          __HIP_MEMORY_SCOPE_AGENT);                          \
    _Pragma("unroll") for (int j_ = 0; j_ < 8; ++j_) q[8 + j_] =              \
        __hip_atomic_load(hp + dB + j_, __ATOMIC_RELAXED,                     \
                          __HIP_MEMORY_SCOPE_AGENT);                          \
  }
#define CHECKQ(q, okv)                                                        \
  {                                                                           \
    bool ok_ = true;                                                          \
    _Pragma("unroll") for (int j_ = 0; j_ < 16; ++j_) ok_ &=                  \
        ((q[j_] >> 16) == want);                                              \
    okv = ok_;                                                                \
  }

  for (int t = 0; t < T_LEN; ++t) {
    const int tx = dir ? (T_LEN - 1 - t) : t;

    // ---- stage x_t from prefetch regs (16B chunks -> 2-way banks, free) ----
    {
      union { _Float16 h[8]; uint4 q; } ua, ub;
#pragma unroll
      for (int j = 0; j < 4; ++j) {
        ua.h[j] = (_Float16)xa0[j];
        ua.h[4 + j] = (_Float16)xa1[j];
        ub.h[j] = (_Float16)xb0[j];
        ub.h[4 + j] = (_Float16)xb1[j];
      }
      *(uint4*)swzA(Alds, ss, dA) = ua.q;
      *(uint4*)swzA(Alds, ss, dB) = ub.q;
    }
    __syncthreads();  // B1

    // ---- prefetch x_{t+1} ----
    {
      const int tn = (t + 1 < T_LEN) ? t + 1 : t;
      const int txn = dir ? (T_LEN - 1 - tn) : tn;
      const float* xr = x + (((bh * 16 + ss) * T_LEN + txn) << 8);
      xa0 = *(const f32x4*)(xr + dA);
      xa1 = *(const f32x4*)(xr + dA + 4);
      xb0 = *(const f32x4*)(xr + dB);
      xb1 = *(const f32x4*)(xr + dB + 4);
    }

    // ---- issue poll sample A before the x-MFMAs (overlap RTT) ----
    u32 qA[16], qB[16];
    const u32* hp = Hg + (((t - 1) & 1) * 16 + ss) * 256;
    const u32 want = (u32)t;
    if (t > 0) LOADQ(qA);

    // ---- x-half MFMAs (K 0..255), acc seeded with biases ----
    f32x4 acc0 = {b0, b0, b0, b0}, acc1 = {b1, b1, b1, b1};
#pragma unroll
    for (int kk = 0; kk < 8; ++kk) {
      f16x8 a = *(const f16x8*)swzA(Alds, l15, kk * 32 + l4 * 8);
      acc0 = __builtin_amdgcn_mfma_f32_16x16x32_f16(a, wB0[kk], acc0, 0, 0, 0);
      acc1 = __builtin_amdgcn_mfma_f32_16x16x32_f16(a, wB1[kk], acc1, 0, 0, 0);
    }

    // ---- poll (2-deep pipelined) + stage h ----
    if (t > 0) {
      bool ok;
      CHECKQ(qA, ok);
      if (!ok) {
        LOADQ(qB);
        for (;;) {
          LOADQ(qA);
          CHECKQ(qB, ok);
          if (ok) {
#pragma unroll
            for (int j = 0; j < 16; ++j) qA[j] = qB[j];
            break;
          }
          LOADQ(qB);
          CHECKQ(qA, ok);
          if (ok) break;
        }
      }
      uint4 pa, pb;
      pa.x = (qA[0] & 0xffffu) | (qA[1] << 16);
      pa.y = (qA[2] & 0xffffu) | (qA[3] << 16);
      pa.z = (qA[4] & 0xffffu) | (qA[5] << 16);
      pa.w = (qA[6] & 0xffffu) | (qA[7] << 16);
      pb.x = (qA[8] & 0xffffu) | (qA[9] << 16);
      pb.y = (qA[10] & 0xffffu) | (qA[11] << 16);
      pb.z = (qA[12] & 0xffffu) | (qA[13] << 16);
      pb.w = (qA[14] & 0xffffu) | (qA[15] << 16);
      *(uint4*)swzA(Alds, ss, 256 + dA) = pa;
      *(uint4*)swzA(Alds, ss, 256 + dB) = pb;
    }
    __syncthreads();  // B2

    // ---- h-half MFMAs (K 256..511) ----
#pragma unroll
    for (int kk = 8; kk < 16; ++kk) {
      f16x8 a = *(const f16x8*)swzA(Alds, l15, kk * 32 + l4 * 8);
      acc0 = __builtin_amdgcn_mfma_f32_16x16x32_f16(a, wB0[kk], acc0, 0, 0, 0);
      acc1 = __builtin_amdgcn_mfma_f32_16x16x32_f16(a, wB1[kk], acc1, 0, 0, 0);
    }

    // ---- in-register cell: lane holds i|f (acc0) and j|o (acc1) ----
    const u32 stamp = ((u32)(t + 1)) << 16;
    u32* pub = Hg + ((t & 1) * 16) * 256 + mw8 + d8;
#pragma unroll
    for (int v = 0; v < 4; ++v) {
      float s0 = sigm(acc0[v]);                    // sigm(i+bi) | sigm(f+bf+1)
      float a1v = acc1[v];
      float uu = lo8 ? a1v + a1v : a1v;
      float s1 = sigm(uu);
      float g1 = lo8 ? 2.f * s1 - 1.f : s1;        // tanh(j+bj) | sigm(o+bo)
      float sf = __shfl_xor(s0, 8);                // lanes<8: sigm(f+1)
      float so = __shfl_xor(g1, 8);                // lanes<8: sigm(o)
      c[v] = c[v] * sf + s0 * g1;
      float tc = 2.f * sigm(c[v] + c[v]) - 1.f;    // tanh(c)
      float h = tc * so;
      if (lo8) {
        union { _Float16 hf; unsigned short us; } cv;
        cv.hf = (_Float16)h;
        const int seq = 4 * l4 + v;
        __hip_atomic_store(pub + seq * 256, stamp | (u32)cv.us,
                           __ATOMIC_RELAXED, __HIP_MEMORY_SCOPE_AGENT);
        __builtin_nontemporal_store(
            h, out + (((bh * 16 + seq) * T_LEN + tx) << 9) + dir * 256 + mw8 + d8);
      }
    }
  }
#undef LOADQ
#undef CHECKQ
}

extern "C" void kernel_launch(void* const* d_in, const int* in_sizes, int n_in,
                              void* d_out, int out_size, void* d_ws,
                              size_t ws_size, hipStream_t stream) {
  const float* x = (const float*)d_in[0];
  const float* Wfw = (const float*)d_in[1];
  const float* bfw = (const float*)d_in[2];
  const float* Wbw = (const float*)d_in[3];
  const float* bbw = (const float*)d_in[4];
  float* out = (float*)d_out;

  // ws: [0, 128KB) stamped h-exchange: 4 groups x 2 bufs x 16 seq x 256 u32
  u32* hglob = (u32*)d_ws;
  (void)hipMemsetAsync(hglob, 0, 4 * 2 * 16 * 256 * sizeof(u32), stream);

  bilstm_kernel<<<dim3(32), dim3(256), 0, stream>>>(x, Wfw, bfw, Wbw, bbw, out,
                                                    hglob);
}

// Round 5
// 4826.263 us; speedup vs baseline: 1.4717x; 1.4717x over previous
//
#include <hip/hip_runtime.h>

#define T_LEN 2048

typedef _Float16 f16x8 __attribute__((ext_vector_type(8)));
typedef float f32x4 __attribute__((ext_vector_type(4)));
typedef unsigned int u32;

__device__ __forceinline__ float sigm(float v) { return 1.f / (1.f + __expf(-v)); }

// XOR-swizzled address into A tile [16 seq][512 k] f16 (row stride 1024B).
__device__ __forceinline__ void* swzA(_Float16* base, int row, int k) {
  int byte = row * 1024 + k * 2;
  byte ^= (row & 7) << 4;
  return (void*)((char*)base + byte);
}

// Grid: 16 WGs x 1024 threads. group g = bid&3 {dir,bh} -> 16 seqs;
// member m = bid>>2 owns h-dims [64m..64m+63] (gate cols p*256+64m+d).
// Wave w (0..15): part p = w>>2, 16 cols at p*256 + 64m + (w&3)*16.
// Exchange: u32 {stamp16|h-f16}, 1 line per (seq,dim), double-buffered by t&1,
// agent-scope relaxed atomics. Per-thread: publish 1 line, poll 3 peer lines.
__global__ __launch_bounds__(1024, 4) void bilstm_kernel(
    const float* __restrict__ x, const float* __restrict__ Wfw,
    const float* __restrict__ bfw, const float* __restrict__ Wbw,
    const float* __restrict__ bbw, float* __restrict__ out,
    u32* __restrict__ hglob) {
  const int g = blockIdx.x & 3;
  const int m = blockIdx.x >> 2;
  const int dir = g >> 1, bh = g & 1;
  const int tid = threadIdx.x;
  const int w = tid >> 6;
  const int lane = tid & 63;
  const int l15 = lane & 15, l4 = lane >> 4;

  const float* W = dir ? Wbw : Wfw;
  const float* bias = dir ? bbw : bfw;

  __shared__ _Float16 Alds[16 * 512];  // 16KB swizzled [seq][k<256:x, k>=256:h]
  __shared__ float Glds[16 * 260];     // gates [seq][256 cols], stride 260

  // ---- weight slice: one 16-col tile x K=512 -> 64 VGPRs ----
  const int p = w >> 2;
  const int cbase = p * 64 + (w & 3) * 16;           // col within WG's 256
  const int gcol = p * 256 + 64 * m + (w & 3) * 16 + l15;
  f16x8 wB[16];
#pragma unroll
  for (int kk = 0; kk < 16; ++kk) {
    const int kb = kk * 32 + l4 * 8;
    f16x8 h;
#pragma unroll
    for (int j = 0; j < 8; ++j) h[j] = (_Float16)W[(kb + j) * 1024 + gcol];
    wB[kk] = h;
  }
  const float bcol = bias[gcol] + ((p == 2) ? 1.f : 0.f);  // forget bias folded

  // ---- per-thread cell/stage/poll mapping: (seq cs, dim cd) ----
  const int cs = tid >> 6;       // 0..15 (== wave id)
  const int cd = tid & 63;       // 0..63
  float c = 0.f;

  u32* Hg = hglob + g * (2 * 16 * 256);
  const int pd1 = 64 * ((m + 1) & 3) + cd;
  const int pd2 = 64 * ((m + 2) & 3) + cd;
  const int pd3 = 64 * ((m + 3) & 3) + cd;
  u32* mypub[2] = {Hg + (0 * 16 + cs) * 256 + 64 * m + cd,
                   Hg + (1 * 16 + cs) * 256 + 64 * m + cd};

  // prologue: zero A h-half (k 256..511), prefetch x_0
  {
    uint2 z = {0u, 0u};
    *(uint2*)swzA(Alds, cs, 256 + 4 * cd) = z;
  }
  const int tx0 = dir ? (T_LEN - 1) : 0;
  f32x4 xv = *(const f32x4*)(x + (((bh * 16 + cs) * T_LEN + tx0) << 8) + 4 * cd);

  for (int t = 0; t < T_LEN; ++t) {
    const int tx = dir ? (T_LEN - 1 - t) : t;

    // ---- stage x_t (4 f32 -> 4 f16, one 8B LDS write) ----
    {
      union { _Float16 h[4]; uint2 q; } ux;
#pragma unroll
      for (int j = 0; j < 4; ++j) ux.h[j] = (_Float16)xv[j];
      *(uint2*)swzA(Alds, cs, 4 * cd) = ux.q;
    }
    __syncthreads();  // B1: x staged (own-h staged by cell of t-1, before this)

    // ---- issue poll samples early (3 lines in flight across x-MFMAs) ----
    const u32 want = (u32)t;
    const u32* Hp = Hg + (((t & 1) ^ 1) * 16 + cs) * 256;
    u32 s1 = 0, s2 = 0, s3 = 0;
    if (t > 0) {
      s1 = __hip_atomic_load(Hp + pd1, __ATOMIC_RELAXED, __HIP_MEMORY_SCOPE_AGENT);
      s2 = __hip_atomic_load(Hp + pd2, __ATOMIC_RELAXED, __HIP_MEMORY_SCOPE_AGENT);
      s3 = __hip_atomic_load(Hp + pd3, __ATOMIC_RELAXED, __HIP_MEMORY_SCOPE_AGENT);
    }

    // ---- prefetch x_{t+1} ----
    {
      const int tn = (t + 1 < T_LEN) ? t + 1 : t;
      const int txn = dir ? (T_LEN - 1 - tn) : tn;
      xv = *(const f32x4*)(x + (((bh * 16 + cs) * T_LEN + txn) << 8) + 4 * cd);
    }

    // ---- x-half MFMAs (K 0..255), acc seeded with bias ----
    f32x4 acc = {bcol, bcol, bcol, bcol};
#pragma unroll
    for (int kk = 0; kk < 8; ++kk) {
      f16x8 a = *(const f16x8*)swzA(Alds, l15, kk * 32 + l4 * 8);
      acc = __builtin_amdgcn_mfma_f32_16x16x32_f16(a, wB[kk], acc, 0, 0, 0);
    }

    // ---- per-thread poll (3 lines), then stage peer h ----
    if (t > 0) {
      while ((s1 >> 16) != want || (s2 >> 16) != want || (s3 >> 16) != want) {
        s1 = __hip_atomic_load(Hp + pd1, __ATOMIC_RELAXED, __HIP_MEMORY_SCOPE_AGENT);
        s2 = __hip_atomic_load(Hp + pd2, __ATOMIC_RELAXED, __HIP_MEMORY_SCOPE_AGENT);
        s3 = __hip_atomic_load(Hp + pd3, __ATOMIC_RELAXED, __HIP_MEMORY_SCOPE_AGENT);
      }
      *(unsigned short*)swzA(Alds, cs, 256 + pd1) = (unsigned short)(s1 & 0xffffu);
      *(unsigned short*)swzA(Alds, cs, 256 + pd2) = (unsigned short)(s2 & 0xffffu);
      *(unsigned short*)swzA(Alds, cs, 256 + pd3) = (unsigned short)(s3 & 0xffffu);
    }
    __syncthreads();  // B2: peer h staged

    // ---- h-half MFMAs (K 256..511) ----
#pragma unroll
    for (int kk = 8; kk < 16; ++kk) {
      f16x8 a = *(const f16x8*)swzA(Alds, l15, kk * 32 + l4 * 8);
      acc = __builtin_amdgcn_mfma_f32_16x16x32_f16(a, wB[kk], acc, 0, 0, 0);
    }

    // ---- gates -> LDS transpose (C/D: col=l15, row=4*l4+v) ----
    {
      float* gw = Glds + cbase + l15;
      const int r = l4 * 4;
#pragma unroll
      for (int v = 0; v < 4; ++v) gw[(r + v) * 260] = acc[v];
    }
    __syncthreads();  // B3: gates ready

    // ---- LSTM cell: thread owns (cs, cd) ----
    const float* Gp = Glds + cs * 260 + cd;
    const float gi = Gp[0 * 64], gj = Gp[1 * 64], gf = Gp[2 * 64], go = Gp[3 * 64];
    c = c * sigm(gf) + sigm(gi) * (2.f * sigm(gj + gj) - 1.f);
    const float h = (2.f * sigm(c + c) - 1.f) * sigm(go);

    // publish (1 u32, wave-contiguous), stage own h locally, store out
    union { _Float16 hf; unsigned short us; } cv;
    cv.hf = (_Float16)h;
    __hip_atomic_store(mypub[t & 1], (((u32)(t + 1)) << 16) | (u32)cv.us,
                       __ATOMIC_RELAXED, __HIP_MEMORY_SCOPE_AGENT);
    *(unsigned short*)swzA(Alds, cs, 256 + 64 * m + cd) = cv.us;
    __builtin_nontemporal_store(
        h, out + (((bh * 16 + cs) * T_LEN + tx) << 9) + dir * 256 + 64 * m + cd);
  }
}

extern "C" void kernel_launch(void* const* d_in, const int* in_sizes, int n_in,
                              void* d_out, int out_size, void* d_ws,
                              size_t ws_size, hipStream_t stream) {
  const float* x = (const float*)d_in[0];
  const float* Wfw = (const float*)d_in[1];
  const float* bfw = (const float*)d_in[2];
  const float* Wbw = (const float*)d_in[3];
  const float* bbw = (const float*)d_in[4];
  float* out = (float*)d_out;

  // ws: 4 groups x 2 bufs x 16 seq x 256 dims x u32 = 128KB stamped h-lines
  u32* hglob = (u32*)d_ws;
  (void)hipMemsetAsync(hglob, 0, 4 * 2 * 16 * 256 * sizeof(u32), stream);

  bilstm_kernel<<<dim3(16), dim3(1024), 0, stream>>>(x, Wfw, bfw, Wbw, bbw, out,
                                                     hglob);
}